// Round 5
// baseline (317.856 us; speedup 1.0000x reference)
//
#include <hip/hip_runtime.h>
#include <hip/hip_bf16.h>

// EdgeGNN: 3x EdgeConv(mean) + final linear.
// Algebra: h'_i = relu( [h_i | mean_j h_j] @ [Wtop - Wbot; Wbot] + b ), 0 if deg==0.
// R11: fused layer kernel — gather-mean + 64x256 GEMM in one dispatch per layer.
// Block (64 rows): 4-node-interleaved gather (8 row-lines in flight/wave) -> Hbar LDS
// [64][264]; GEMM A-top staged from Ucat (k<256), A-bottom from Hbar LDS (k>=256),
// bn=0..3 inner loop over output col-blocks; fused relu/bias/deg-mask epilogue.
// Removes 3 agg launches + 20MB/layer Hbar round-trip; gather overlaps GEMM across the
// 3 resident blocks/CU. scan (R10 parallel), setup, fill, final GEMM unchanged.

typedef short short8 __attribute__((ext_vector_type(8)));
typedef unsigned short ushort8v __attribute__((ext_vector_type(8)));
typedef float float4v __attribute__((ext_vector_type(4)));

static __device__ __forceinline__ float bf2f(unsigned short u) {
    union { unsigned int i; float f; } c; c.i = ((unsigned int)u) << 16; return c.f;
}
static __device__ __forceinline__ unsigned short f2bf(float f) {
    union { float f; unsigned int i; } c; c.f = f;
    unsigned int u = c.i;
    return (unsigned short)((u + 0x7FFFu + ((u >> 16) & 1u)) >> 16);  // RNE
}

// ---------------- fused setup: deg count + weight prep + x->bf16 ----------------
__global__ __launch_bounds__(256)
void setup_kernel(const int* __restrict__ dst, int E, int* __restrict__ deg,
                  const float* __restrict__ W0, const float* __restrict__ W1,
                  const float* __restrict__ W2, const float* __restrict__ Wf,
                  const float* __restrict__ x,
                  unsigned short* __restrict__ Wc0, unsigned short* __restrict__ Wc1,
                  unsigned short* __restrict__ Wc2, unsigned short* __restrict__ Wft,
                  unsigned short* __restrict__ Ucat, int N, int EB) {
    __shared__ float ta[32][33];
    __shared__ float tb[32][33];
    int bb = blockIdx.x;
    int t = threadIdx.x;
    if (bb < EB) {
        int idx = bb * 256 + t;
        if (idx < E) atomicAdd(&deg[dst[idx]], 1);
        return;
    }
    int bb2 = bb - EB;
    int r0 = t >> 5, c = t & 31;
    if (bb2 < 192) {
        const float* W = (bb2 < 64) ? W0 : (bb2 < 128) ? W1 : W2;
        unsigned short* Wc = (bb2 < 64) ? Wc0 : (bb2 < 128) ? Wc1 : Wc2;
        int t64 = bb2 & 63;
        int k0 = (t64 >> 3) * 32, n0 = (t64 & 7) * 32;
#pragma unroll
        for (int it = 0; it < 4; ++it) {
            int r = r0 + it * 8;
            float a = W[(k0 + r) * 256 + n0 + c];
            float bv = W[(k0 + r + 256) * 256 + n0 + c];
            ta[r][c] = a - bv;
            tb[r][c] = bv;
        }
        __syncthreads();
#pragma unroll
        for (int it = 0; it < 4; ++it) {
            int r = r0 + it * 8;  // row in n-space
            Wc[(n0 + r) * 512 + k0 + c] = f2bf(ta[c][r]);
            Wc[(n0 + r) * 512 + 256 + k0 + c] = f2bf(tb[c][r]);
        }
    } else if (bb2 < 448) {
        int t256 = bb2 - 192;
        int k0 = (t256 >> 3) * 32, n0 = (t256 & 7) * 32;
#pragma unroll
        for (int it = 0; it < 4; ++it) {
            int r = r0 + it * 8;
            ta[r][c] = Wf[(k0 + r) * 256 + n0 + c];
        }
        __syncthreads();
#pragma unroll
        for (int it = 0; it < 4; ++it) {
            int r = r0 + it * 8;
            Wft[(n0 + r) * 1024 + k0 + c] = f2bf(ta[c][r]);
        }
    } else {
        long base = (long)(bb2 - 448) * 2048 + t * 8;
        if (base < (long)N * 256) {
            int i = (int)(base >> 8), cc = (int)(base & 255);
            const float4* xp = (const float4*)(x + base);
            float4 v0 = xp[0], v1 = xp[1];
            ushort4 w0, w1;
            w0.x = f2bf(v0.x); w0.y = f2bf(v0.y); w0.z = f2bf(v0.z); w0.w = f2bf(v0.w);
            w1.x = f2bf(v1.x); w1.y = f2bf(v1.y); w1.z = f2bf(v1.z); w1.w = f2bf(v1.w);
            unsigned short* up = Ucat + (long)i * 1024 + cc;
            *(ushort4*)up = w0;
            *(ushort4*)(up + 4) = w1;
        }
    }
}

// ---------------- CSR scan (redundant-prefix, parallel blocks) ----------------
__global__ __launch_bounds__(256)
void scan_kernel(const int* __restrict__ deg, int* __restrict__ offs,
                 int* __restrict__ cursor, int N) {
    __shared__ int part[256];
    __shared__ int pre[128];
    int b = blockIdx.x, t = threadIdx.x;
    int beg = b * 128;
    int end = beg + 128; if (end > N) end = N;
    // phase 1: base = sum deg[0..beg)
    int s = 0;
    for (int i = t; i < beg; i += 256) s += deg[i];
    part[t] = s;
    __syncthreads();
#pragma unroll
    for (int off = 128; off > 0; off >>= 1) {
        if (t < off) part[t] += part[t + off];
        __syncthreads();
    }
    int base = part[0];
    // phase 2: local inclusive scan of deg[beg..end)
    int cnt = end - beg;
    if (t < 128) pre[t] = (t < cnt) ? deg[beg + t] : 0;
    __syncthreads();
    for (int off = 1; off < 128; off <<= 1) {
        int v = 0;
        if (t < 128 && t >= off) v = pre[t - off];
        __syncthreads();
        if (t < 128 && t >= off) pre[t] += v;
        __syncthreads();
    }
    if (t < cnt) {
        int excl = base + (t ? pre[t - 1] : 0);
        offs[beg + t] = excl;
        cursor[beg + t] = excl;
    }
    if (end == N && t == 0) offs[N] = base + (cnt ? pre[cnt - 1] : 0);
}

__global__ void fill_kernel(const int* __restrict__ src, const int* __restrict__ dst, int E,
                            int* __restrict__ cursor, int* __restrict__ esrc) {
    int idx = blockIdx.x * 256 + threadIdx.x;
    if (idx < E) {
        int p = atomicAdd(&cursor[dst[idx]], 1);
        esrc[p] = src[idx];
    }
}

// ---------------- fused layer: gather-mean + GEMM (64 rows x 256 cols per block) ------
// hb: Hbar tile [64][264] bf16 during GEMM (A for k>=256); reused as C tile in epilogue.
// sa: A chunk [64][72] (kc<4, staged from Ucat rows). sb: B chunk [64][72] per (kc,bn).
// Gather: per wave 16 nodes in 4 batches of 4 interleaved slots; per slot-iter 4 edges
// via two two-row loads (lanes 0-31 = even edge, 32-63 = odd); clamped + fma-masked.
__global__ __launch_bounds__(256, 3)
void layer_kernel(const unsigned short* __restrict__ A1,   // Ucat + l*256 (stride 1024)
                  const int* __restrict__ offs,
                  const int* __restrict__ esrc,
                  const unsigned short* __restrict__ Bt,   // Wc[l] [256 n][512 k]
                  const float* __restrict__ bias,
                  const int* __restrict__ deg,
                  unsigned short* __restrict__ outB,       // Ucat + (l+1)*256
                  int N) {
    __shared__ __align__(16) unsigned short hb[64 * 264];  // 33792 B
    __shared__ __align__(16) unsigned short sa[64 * 72];   // 9216 B
    __shared__ __align__(16) unsigned short sb[64 * 72];   // 9216 B
    int t = threadIdx.x;
    int bm = blockIdx.x;
    int lane = t & 63, wave = t >> 6;

    // ---------- gather phase ----------
    {
        int half = lane >> 5;
        int c = (lane & 31) * 8;
        int nb = wave * 16;
        for (int batch = 0; batch < 4; ++batch) {
            float ac[4][8];
#pragma unroll
            for (int s = 0; s < 4; ++s)
#pragma unroll
                for (int j = 0; j < 8; ++j) ac[s][j] = 0.f;
            int e_[4], f_[4], d_[4];
#pragma unroll
            for (int s = 0; s < 4; ++s) {
                int gi = bm * 64 + nb + batch * 4 + s;
                int a0 = 0, a1 = 0;
                if (gi < N) { a0 = offs[gi]; a1 = offs[gi + 1]; }
                e_[s] = a0; f_[s] = a1; d_[s] = a1 - a0;
            }
            while ((e_[0] < f_[0]) | (e_[1] < f_[1]) | (e_[2] < f_[2]) | (e_[3] < f_[3])) {
                ushort8v r0[4], r1[4];
                float m0[4], m1[4];
#pragma unroll
                for (int s = 0; s < 4; ++s) {
                    int e = e_[s], f = f_[s];
                    int last = (f > 0) ? f - 1 : 0;
                    int i0 = e + half;
                    int i1 = e + 2 + half;
                    int c0 = (i0 < f) ? i0 : last;
                    int c1 = (i1 < f) ? i1 : last;
                    m0[s] = (i0 < f) ? 1.f : 0.f;
                    m1[s] = (i1 < f) ? 1.f : 0.f;
                    int s0 = esrc[c0], s1 = esrc[c1];
                    r0[s] = *(const ushort8v*)(A1 + (long)s0 * 1024 + c);
                    r1[s] = *(const ushort8v*)(A1 + (long)s1 * 1024 + c);
                }
#pragma unroll
                for (int s = 0; s < 4; ++s)
#pragma unroll
                    for (int j = 0; j < 8; ++j) {
                        ac[s][j] = fmaf(bf2f(r0[s][j]), m0[s], ac[s][j]);
                        ac[s][j] = fmaf(bf2f(r1[s][j]), m1[s], ac[s][j]);
                    }
#pragma unroll
                for (int s = 0; s < 4; ++s) e_[s] += 4;
            }
#pragma unroll
            for (int s = 0; s < 4; ++s) {
                int il = nb + batch * 4 + s;
                float inv = (d_[s] > 0) ? 1.0f / (float)d_[s] : 0.0f;
                ushort8v w;
#pragma unroll
                for (int j = 0; j < 8; ++j) {
                    float ts = ac[s][j] + __shfl_xor(ac[s][j], 32);
                    w[j] = f2bf(ts * inv);
                }
                if (half == 0) *(ushort8v*)(hb + il * 264 + c) = w;
            }
        }
    }
    // no barrier needed yet: first LDS consumer below is preceded by __syncthreads

    // ---------- GEMM phase: C[64][256] = [Ucat | Hbar] @ Bt^T ----------
    int wm = wave >> 1, wn = wave & 1;   // wave grid 2x2 over (64 rows x 64 cols-within-bn)
    int lr = lane & 15, q = lane >> 4;
    float4v acc[4][2][2];
#pragma unroll
    for (int bn = 0; bn < 4; ++bn)
#pragma unroll
        for (int i = 0; i < 2; ++i)
#pragma unroll
            for (int j = 0; j < 2; ++j) { float4v z = {0.f, 0.f, 0.f, 0.f}; acc[bn][i][j] = z; }

    int r = t >> 2, quarter = t & 3;
    int rowA = bm * 64 + r; if (rowA >= N) rowA = N - 1;   // clamp; stores masked
    const unsigned short* gA = A1 + (long)rowA * 1024 + quarter * 16;
    unsigned short* sAp = sa + r * 72 + quarter * 16;
    const unsigned short* gB = Bt + (long)r * 512 + quarter * 16;
    unsigned short* sBp = sb + r * 72 + quarter * 16;

    for (int kc = 0; kc < 8; ++kc) {
        uint4 a0v, a1v;
        bool hasA = kc < 4;
        if (hasA) {
            const unsigned short* p = gA + kc * 64;
            a0v = *(const uint4*)p; a1v = *(const uint4*)(p + 8);
        }
#pragma unroll
        for (int bn = 0; bn < 4; ++bn) {
            const unsigned short* pb = gB + (long)bn * 64 * 512 + kc * 64;
            uint4 b0v = *(const uint4*)pb;
            uint4 b1v = *(const uint4*)(pb + 8);
            __syncthreads();   // prior MFMA reads of sa/sb done (also orders gather writes)
            *(uint4*)sBp = b0v; *(uint4*)(sBp + 8) = b1v;
            if (bn == 0 && hasA) { *(uint4*)sAp = a0v; *(uint4*)(sAp + 8) = a1v; }
            __syncthreads();
#pragma unroll
            for (int ks = 0; ks < 2; ++ks) {
                short8 af[2], bfv[2];
#pragma unroll
                for (int mi = 0; mi < 2; ++mi) {
                    int row = wm * 32 + mi * 16 + lr;
                    af[mi] = hasA
                        ? *(const short8*)(sa + row * 72 + ks * 32 + q * 8)
                        : *(const short8*)(hb + row * 264 + (kc - 4) * 64 + ks * 32 + q * 8);
                }
#pragma unroll
                for (int ni = 0; ni < 2; ++ni)
                    bfv[ni] = *(const short8*)(sb + (wn * 32 + ni * 16 + lr) * 72 + ks * 32 + q * 8);
#pragma unroll
                for (int mi = 0; mi < 2; ++mi)
#pragma unroll
                    for (int ni = 0; ni < 2; ++ni)
                        acc[bn][mi][ni] = __builtin_amdgcn_mfma_f32_16x16x32_bf16(
                            af[mi], bfv[ni], acc[bn][mi][ni], 0, 0, 0);
            }
        }
    }

    // ---------- epilogue: relu+bias, C -> hb [64][264], coalesced 16B stores ----------
    __syncthreads();   // all MFMA reads of hb done
#pragma unroll
    for (int bn = 0; bn < 4; ++bn) {
#pragma unroll
        for (int mi = 0; mi < 2; ++mi) {
#pragma unroll
            for (int ni = 0; ni < 2; ++ni) {
                int cn = bn * 64 + wn * 32 + ni * 16 + lr;
                float bv = bias[cn];
                int rl0 = wm * 32 + mi * 16 + q * 4;
#pragma unroll
                for (int r4 = 0; r4 < 4; ++r4) {
                    float v = fmaxf(acc[bn][mi][ni][r4] + bv, 0.0f);
                    hb[(rl0 + r4) * 264 + cn] = f2bf(v);
                }
            }
        }
    }
    __syncthreads();
#pragma unroll
    for (int j = 0; j < 8; ++j) {
        int chunk = t + j * 256;        // 2048 chunks: 64 rows x 32 x 16B
        int row = chunk >> 5, h = chunk & 31;
        int rg = bm * 64 + row;
        if (rg < N) {
            short8 v = *(const short8*)(hb + row * 264 + h * 8);
            if (deg[rg] <= 0) { short8 z = {0, 0, 0, 0, 0, 0, 0, 0}; v = z; }
            *(short8*)(outB + (long)rg * 1024 + h * 8) = v;
        }
    }
}

// ---------------- bf16 MFMA GEMM (final linear), 64x64 tile ----------------
#define LDK 72

template <int MODE, int K>
__global__ __launch_bounds__(256)
void gemm_kernel(const unsigned short* __restrict__ A1,
                 const unsigned short* __restrict__ A2,
                 const unsigned short* __restrict__ Bt,
                 const float* __restrict__ bias,
                 const int* __restrict__ deg,
                 unsigned short* __restrict__ outB,
                 float* __restrict__ outF,
                 int M) {
    __shared__ __align__(16) unsigned char smem[64 * LDK * 2 * 2];  // 18432 B
    unsigned short* ldsA = (unsigned short*)smem;
    unsigned short* ldsB = ldsA + 64 * LDK;
    constexpr int NIT = K / 64;
    int t = threadIdx.x;
    int bm = blockIdx.x, bn = blockIdx.y;
    int lane = t & 63, wave = t >> 6;
    int wm = wave >> 1, wn = wave & 1;
    int lr = lane & 15, q = lane >> 4;

    float4v acc[2][2];
#pragma unroll
    for (int i = 0; i < 2; i++)
#pragma unroll
        for (int j = 0; j < 2; j++) { float4v z = {0.f, 0.f, 0.f, 0.f}; acc[i][j] = z; }

    int r = t >> 2;
    int quarter = t & 3;
    int rowA = bm * 64 + r;
    if (rowA >= M) rowA = M - 1;
    const unsigned short* gB0 = Bt + (long)(bn * 64 + r) * K + quarter * 16;
    unsigned short* sA = ldsA + r * LDK + quarter * 16;
    unsigned short* sB = ldsB + r * LDK + quarter * 16;

    auto addrA = [&](int kk) -> const unsigned short* {
        if (MODE == 1 || kk < 256) return A1 + (long)rowA * 1024 + kk + quarter * 16;
        return A2 + (long)rowA * 256 + (kk - 256) + quarter * 16;
    };

    const unsigned short* pa = addrA(0);
    uint4 a0 = *(const uint4*)pa;
    uint4 a1 = *(const uint4*)(pa + 8);
    uint4 b0 = *(const uint4*)gB0;
    uint4 b1 = *(const uint4*)(gB0 + 8);

    for (int it = 0; it < NIT; ++it) {
        __syncthreads();
        *(uint4*)sA = a0; *(uint4*)(sA + 8) = a1;
        *(uint4*)sB = b0; *(uint4*)(sB + 8) = b1;
        __syncthreads();
        if (it + 1 < NIT) {
            int kn = (it + 1) << 6;
            const unsigned short* pn = addrA(kn);
            a0 = *(const uint4*)pn;
            a1 = *(const uint4*)(pn + 8);
            b0 = *(const uint4*)(gB0 + kn);
            b1 = *(const uint4*)(gB0 + kn + 8);
        }
#pragma unroll
        for (int ks = 0; ks < 2; ++ks) {
            short8 af[2], bfr[2];
#pragma unroll
            for (int mi = 0; mi < 2; ++mi)
                af[mi] = *(const short8*)(ldsA + (wm * 32 + mi * 16 + lr) * LDK + ks * 32 + q * 8);
#pragma unroll
            for (int ni = 0; ni < 2; ++ni)
                bfr[ni] = *(const short8*)(ldsB + (wn * 32 + ni * 16 + lr) * LDK + ks * 32 + q * 8);
#pragma unroll
            for (int mi = 0; mi < 2; ++mi)
#pragma unroll
                for (int ni = 0; ni < 2; ++ni)
                    acc[mi][ni] = __builtin_amdgcn_mfma_f32_16x16x32_bf16(af[mi], bfr[ni], acc[mi][ni], 0, 0, 0);
        }
    }

    __syncthreads();

    if (MODE == 0) {
        unsigned short* C = (unsigned short*)smem;
#pragma unroll
        for (int mi = 0; mi < 2; ++mi) {
#pragma unroll
            for (int ni = 0; ni < 2; ++ni) {
                int cn = wn * 32 + ni * 16 + lr;
                float bv = bias[bn * 64 + cn];
                int rl0 = wm * 32 + mi * 16 + q * 4;
#pragma unroll
                for (int r4 = 0; r4 < 4; ++r4) {
                    float v = fmaxf(acc[mi][ni][r4] + bv, 0.0f);
                    C[(rl0 + r4) * LDK + cn] = f2bf(v);
                }
            }
        }
        __syncthreads();
#pragma unroll
        for (int j = 0; j < 2; ++j) {
            int chunk = t + j * 256;
            int row = chunk >> 3, h = chunk & 7;
            int rg = bm * 64 + row;
            if (rg < M) {
                short8 v = *(const short8*)(C + row * LDK + h * 8);
                if (deg[rg] <= 0) { short8 z = {0, 0, 0, 0, 0, 0, 0, 0}; v = z; }
                *(short8*)(outB + (long)rg * 1024 + bn * 64 + h * 8) = v;
            }
        }
    } else {
        float* Cf = (float*)smem;
#pragma unroll
        for (int mi = 0; mi < 2; ++mi) {
#pragma unroll
            for (int ni = 0; ni < 2; ++ni) {
                int cn = wn * 32 + ni * 16 + lr;
                float bv = bias[bn * 64 + cn];
                int rl0 = wm * 32 + mi * 16 + q * 4;
#pragma unroll
                for (int r4 = 0; r4 < 4; ++r4)
                    Cf[(rl0 + r4) * 68 + cn] = acc[mi][ni][r4] + bv;
            }
        }
        __syncthreads();
#pragma unroll
        for (int j = 0; j < 4; ++j) {
            int chunk = t + j * 256;
            int row = chunk >> 4, h = chunk & 15;
            int rg = bm * 64 + row;
            if (rg < M) {
                float4 v = *(const float4*)(Cf + row * 68 + h * 4);
                *(float4*)(outF + (long)rg * 256 + bn * 64 + h * 4) = v;
            }
        }
    }
}

extern "C" void kernel_launch(void* const* d_in, const int* in_sizes, int n_in,
                              void* d_out, int out_size, void* d_ws, size_t ws_size,
                              hipStream_t stream) {
    const float* x = (const float*)d_in[0];
    const int* ei = (const int*)d_in[1];
    const float* W[3] = {(const float*)d_in[2], (const float*)d_in[4], (const float*)d_in[6]};
    const float* b[3] = {(const float*)d_in[3], (const float*)d_in[5], (const float*)d_in[7]};
    const float* Wfp = (const float*)d_in[8];
    const float* bfp = (const float*)d_in[9];

    int N = in_sizes[0] / 256;
    int E = in_sizes[1] / 2;
    const int* src = ei;
    const int* dst = ei + E;

    char* p = (char*)d_ws;
    auto alloc = [&](size_t bytes) { char* r = p; p += (bytes + 255) & ~(size_t)255; return r; };
    int* deg = (int*)alloc((size_t)N * 4);
    int* offs = (int*)alloc((size_t)(N + 1) * 4);
    int* cursor = (int*)alloc((size_t)N * 4);
    int* esrc = (int*)alloc((size_t)E * 4);
    unsigned short* Wc[3];
    for (int l = 0; l < 3; l++) Wc[l] = (unsigned short*)alloc(256 * 512 * 2);
    unsigned short* Wft = (unsigned short*)alloc(256 * 1024 * 2);
    unsigned short* Ucat = (unsigned short*)alloc((size_t)N * 1024 * 2);

    hipMemsetAsync(deg, 0, (size_t)N * 4, stream);
    int EB = (E + 255) / 256;
    int xblocks = (N * 256 + 2047) / 2048;
    setup_kernel<<<EB + 448 + xblocks, 256, 0, stream>>>(dst, E, deg, W[0], W[1], W[2], Wfp, x,
                                                         Wc[0], Wc[1], Wc[2], Wft, Ucat, N, EB);
    int nb = (N + 127) / 128;
    scan_kernel<<<nb, 256, 0, stream>>>(deg, offs, cursor, N);
    fill_kernel<<<EB, 256, 0, stream>>>(src, dst, E, cursor, esrc);

    int gm = (N + 63) / 64;   // 313
    for (int l = 0; l < 3; l++) {
        layer_kernel<<<gm, 256, 0, stream>>>(Ucat + l * 256, offs, esrc, Wc[l], b[l],
                                             deg, Ucat + (l + 1) * 256, N);
    }
    gemm_kernel<1, 1024><<<dim3(gm, 4), 256, 0, stream>>>(Ucat, nullptr, Wft, bfp, nullptr,
                                                          nullptr, (float*)d_out, N);
}